// Round 9
// baseline (654.987 us; speedup 1.0000x reference)
//
#include <hip/hip_runtime.h>
#include <hip/hip_cooperative_groups.h>
#include <math.h>
#include <float.h>

namespace cg = cooperative_groups;

#define DDIM 1024   // D
#define PDIM 32     // pattern_dim
#define NPAT 256    // n_patterns
#define TOPK 4
#define BLOCK 256
#define GT   16     // tokens per tile
#define DCH  256    // d-chunk per block
#define NCH  4      // d-chunks (DDIM/DCH)
#define RTPB 4      // tokens per route block (one per wave)
#define GRID 512    // cooperative grid: 2 blocks/CU x 256 CUs

// ===========================================================================
// Fused cooperative kernel: route -> scanfill -> proj -> up -> combine
// with grid.sync() between phases. All phase logic is verbatim from the
// R8-verified standalone kernels; no early returns (coop-sync safety).
// LDS: union of per-phase layouts, ~57 KB -> exactly 2 blocks/CU.
// ===========================================================================
__global__ __launch_bounds__(BLOCK, 2) void fused_kernel(
    const float* __restrict__ x,
    const float* __restrict__ hasher_w,
    const float* __restrict__ keys,
    const float* __restrict__ vd,
    const float* __restrict__ vu,
    const float* __restrict__ scale_p,
    float* __restrict__ out,
    int*   __restrict__ tki,
    float* __restrict__ tkw,
    int*   __restrict__ offs,
    int*   __restrict__ etok,
    float* __restrict__ ew,
    int*   __restrict__ slotof,
    float* __restrict__ part,
    float* __restrict__ contrib,
    int ntok, int nent)
{
    __shared__ union {
        struct { float P[RTPB][64 * 33]; float h[RTPB][32]; } rt;    // 34.3 KB
        struct { int s[NPAT]; int cur[NPAT]; } sf;                   // 2 KB
        struct { float vdl[DCH * PDIM]; float xl[GT * DCH];
                 float red[4][8][68]; int gt[GT]; int gs[GT]; } pj;  // 56.8 KB
        struct { float vul[PDIM * DCH]; float projT[PDIM][20];
                 int gt[GT]; float gw[GT]; int gs[GT]; } up;         // 35 KB
    } sh;

    cg::grid_group grid = cg::this_grid();
    const int tid  = threadIdx.x;
    const int wv   = tid >> 6;
    const int lane = tid & 63;

    // ------------------------------------------------------------ phase 1: route
    for (int tb = blockIdx.x * RTPB; tb < ntok; tb += gridDim.x * RTPB) {
        const int tok = min(tb + wv, ntok - 1);    // clamp: dup compute, guarded write

        const float4* xrow = (const float4*)(x + (size_t)tok * DDIM);
        float4 xr[4];
        #pragma unroll
        for (int i = 0; i < 4; ++i) xr[i] = xrow[i * 64 + lane];

        float hpart[PDIM];
        #pragma unroll
        for (int pp = 0; pp < PDIM; ++pp) {
            const float4* wrow = (const float4*)(hasher_w + (size_t)pp * DDIM);
            float a = 0.f;
            #pragma unroll
            for (int i = 0; i < 4; ++i) {
                const float4 w4 = wrow[i * 64 + lane];
                a = fmaf(xr[i].x, w4.x, a); a = fmaf(xr[i].y, w4.y, a);
                a = fmaf(xr[i].z, w4.z, a); a = fmaf(xr[i].w, w4.w, a);
            }
            hpart[pp] = a;
        }

        float* P = sh.rt.P[wv];
        #pragma unroll
        for (int pp = 0; pp < PDIM; ++pp) P[lane * 33 + pp] = hpart[pp];
        __syncthreads();

        {
            const int pp = lane & 31, half = lane >> 5;
            float hsum = 0.f;
            #pragma unroll 8
            for (int i = 0; i < 32; ++i)
                hsum += P[(half * 32 + i) * 33 + pp];
            hsum += __shfl_xor(hsum, 32, 64);
            if (half == 0) sh.rt.h[wv][pp] = hsum;
        }
        __syncthreads();

        float4 h4[8];
        #pragma unroll
        for (int i = 0; i < 8; ++i) h4[i] = *(const float4*)&sh.rt.h[wv][i * 4];

        float sc0, sc1, sc2, sc3;
        {
            float sv[4];
            #pragma unroll
            for (int c = 0; c < 4; ++c) {
                const float4* kr = (const float4*)(keys + (size_t)(c * 64 + lane) * PDIM);
                float a = 0.f;
                #pragma unroll
                for (int i = 0; i < 8; ++i) {
                    const float4 k4 = kr[i];
                    a = fmaf(k4.x, h4[i].x, a); a = fmaf(k4.y, h4[i].y, a);
                    a = fmaf(k4.z, h4[i].z, a); a = fmaf(k4.w, h4[i].w, a);
                }
                sv[c] = a;
            }
            sc0 = sv[0]; sc1 = sv[1]; sc2 = sv[2]; sc3 = sv[3];
        }

        float wval[TOPK]; int widx[TOPK];
        #pragma unroll
        for (int r = 0; r < TOPK; ++r) {
            float bv = sc0; int bc = 0;
            if (sc1 > bv) { bv = sc1; bc = 1; }
            if (sc2 > bv) { bv = sc2; bc = 2; }
            if (sc3 > bv) { bv = sc3; bc = 3; }
            int bidx = bc * 64 + lane;
            #pragma unroll
            for (int off = 1; off < 64; off <<= 1) {
                const float ov = __shfl_xor(bv, off, 64);
                const int   oi = __shfl_xor(bidx, off, 64);
                if (ov > bv || (ov == bv && oi < bidx)) { bv = ov; bidx = oi; }
            }
            wval[r] = bv; widx[r] = bidx;
            if ((bidx & 63) == lane) {
                const int c = bidx >> 6;
                if (c == 0) sc0 = -FLT_MAX;
                else if (c == 1) sc1 = -FLT_MAX;
                else if (c == 2) sc2 = -FLT_MAX;
                else sc3 = -FLT_MAX;
            }
        }

        if (lane == 0 && tb + wv < ntok) {
            float m = wval[0];
            #pragma unroll
            for (int k = 1; k < TOPK; ++k) m = fmaxf(m, wval[k]);
            float s = 0.f, e[TOPK];
            #pragma unroll
            for (int k = 0; k < TOPK; ++k) { e[k] = expf(wval[k] - m); s += e[k]; }
            #pragma unroll
            for (int k = 0; k < TOPK; ++k) {
                tki[tok * TOPK + k] = widx[k];
                tkw[tok * TOPK + k] = e[k] / s;
            }
        }
        __syncthreads();
    }

    grid.sync();

    // ------------------------------------------------------------ phase 2: scanfill (block 0)
    if (blockIdx.x == 0) {
        sh.sf.cur[tid] = 0;
        __syncthreads();
        for (int e = tid; e < nent; e += NPAT) atomicAdd(&sh.sf.cur[tki[e]], 1);
        __syncthreads();

        const int v = sh.sf.cur[tid];
        sh.sf.s[tid] = v;
        __syncthreads();
        for (int off = 1; off < NPAT; off <<= 1) {
            int t = 0;
            if (tid >= off) t = sh.sf.s[tid - off];
            __syncthreads();
            sh.sf.s[tid] += t;
            __syncthreads();
        }
        const int incl = sh.sf.s[tid];
        offs[tid + 1] = incl;
        if (tid == 0) offs[0] = 0;
        sh.sf.cur[tid] = incl - v;
        __syncthreads();

        const float sc = scale_p[0];
        for (int e = tid; e < nent; e += NPAT) {
            const int p = tki[e];
            const int slot = atomicAdd(&sh.sf.cur[p], 1);
            etok[slot] = e >> 2;
            ew[slot]   = tkw[e] * sc;
            slotof[e]  = slot;
        }
    }

    grid.sync();

    // ------------------------------------------------------------ phase 3: proj
    for (int pc = blockIdx.x; pc < NPAT * NCH; pc += gridDim.x) {
        const int p = pc >> 2;
        const int c = pc & 3;
        const int off0 = offs[p];
        const int n    = offs[p + 1] - off0;
        if (n == 0) continue;

        const float* vdp = vd + (size_t)p * DDIM * PDIM + (size_t)c * DCH * PDIM;
        #pragma unroll
        for (int k = 0; k < 8; ++k)
            ((float4*)sh.pj.vdl)[k * 256 + tid] = ((const float4*)vdp)[k * 256 + tid];
        __syncthreads();

        const int pp4 = tid & 7;
        const int seg = tid >> 3;
        float* partc = part + (size_t)c * (size_t)(nent + 1) * PDIM;

        for (int t0 = 0; t0 < n; t0 += GT) {
            const int gv = min(GT, n - t0);
            if (tid < GT) {
                if (tid < gv) { sh.pj.gt[tid] = etok[off0 + t0 + tid]; sh.pj.gs[tid] = off0 + t0 + tid; }
                else          { sh.pj.gt[tid] = etok[off0];            sh.pj.gs[tid] = nent; }
            }
            __syncthreads();

            #pragma unroll
            for (int k = 0; k < 4; ++k) {
                const int q  = k * 256 + tid;
                const int g  = q >> 6, fi = q & 63;
                ((float4*)sh.pj.xl)[g * 64 + fi] =
                    *(const float4*)(x + (size_t)sh.pj.gt[g] * DDIM + c * DCH + fi * 4);
            }
            __syncthreads();

            float4 acc[GT];
            #pragma unroll
            for (int g = 0; g < GT; ++g) acc[g] = make_float4(0.f, 0.f, 0.f, 0.f);

            #pragma unroll
            for (int i4 = 0; i4 < 2; ++i4) {
                const int d0 = seg * 8 + i4 * 4;
                const float4 v0 = *(const float4*)&sh.pj.vdl[(d0 + 0) * PDIM + pp4 * 4];
                const float4 v1 = *(const float4*)&sh.pj.vdl[(d0 + 1) * PDIM + pp4 * 4];
                const float4 v2 = *(const float4*)&sh.pj.vdl[(d0 + 2) * PDIM + pp4 * 4];
                const float4 v3 = *(const float4*)&sh.pj.vdl[(d0 + 3) * PDIM + pp4 * 4];
                #pragma unroll
                for (int g = 0; g < GT; ++g) {
                    const float4 xg = *(const float4*)&sh.pj.xl[g * DCH + d0];
                    acc[g].x = fmaf(xg.x, v0.x, acc[g].x);
                    acc[g].y = fmaf(xg.x, v0.y, acc[g].y);
                    acc[g].z = fmaf(xg.x, v0.z, acc[g].z);
                    acc[g].w = fmaf(xg.x, v0.w, acc[g].w);
                    acc[g].x = fmaf(xg.y, v1.x, acc[g].x);
                    acc[g].y = fmaf(xg.y, v1.y, acc[g].y);
                    acc[g].z = fmaf(xg.y, v1.z, acc[g].z);
                    acc[g].w = fmaf(xg.y, v1.w, acc[g].w);
                    acc[g].x = fmaf(xg.z, v2.x, acc[g].x);
                    acc[g].y = fmaf(xg.z, v2.y, acc[g].y);
                    acc[g].z = fmaf(xg.z, v2.z, acc[g].z);
                    acc[g].w = fmaf(xg.z, v2.w, acc[g].w);
                    acc[g].x = fmaf(xg.w, v3.x, acc[g].x);
                    acc[g].y = fmaf(xg.w, v3.y, acc[g].y);
                    acc[g].z = fmaf(xg.w, v3.z, acc[g].z);
                    acc[g].w = fmaf(xg.w, v3.w, acc[g].w);
                }
            }

            #pragma unroll
            for (int g = 0; g < GT; ++g) {
                #pragma unroll
                for (int off = 8; off <= 32; off <<= 1) {
                    acc[g].x += __shfl_xor(acc[g].x, off, 64);
                    acc[g].y += __shfl_xor(acc[g].y, off, 64);
                    acc[g].z += __shfl_xor(acc[g].z, off, 64);
                    acc[g].w += __shfl_xor(acc[g].w, off, 64);
                }
            }
            const int w4v = tid >> 6;
            if ((tid & 0x38) == 0) {
                #pragma unroll
                for (int g = 0; g < GT; ++g)
                    *(float4*)&sh.pj.red[w4v][pp4][g * 4] = acc[g];
            }
            __syncthreads();

            #pragma unroll
            for (int r = 0; r < 2; ++r) {
                const int idx = tid + r * BLOCK;
                const int g = idx >> 5, pp = idx & 31;
                const int q = pp >> 2, cmp = g * 4 + (pp & 3);
                const float s = sh.pj.red[0][q][cmp] + sh.pj.red[1][q][cmp]
                              + sh.pj.red[2][q][cmp] + sh.pj.red[3][q][cmp];
                partc[(size_t)sh.pj.gs[g] * PDIM + pp] = s;
            }
            __syncthreads();
        }
        __syncthreads();
    }

    grid.sync();

    // ------------------------------------------------------------ phase 4: up (MODE 0)
    for (int pc = blockIdx.x; pc < NPAT * NCH; pc += gridDim.x) {
        const int p = pc >> 2;
        const int c = pc & 3;
        const int off0 = offs[p];
        const int n    = offs[p + 1] - off0;
        if (n == 0) continue;

        const size_t PS = (size_t)(nent + 1) * PDIM;

        const float* vup = vu + (size_t)p * PDIM * DDIM + (size_t)c * DCH;
        #pragma unroll
        for (int k = 0; k < 8; ++k) {
            const int q  = k * 256 + tid;
            const int pp = q >> 6, fi = q & 63;
            *(float4*)&sh.up.vul[pp * DCH + fi * 4] =
                *(const float4*)(vup + (size_t)pp * DDIM + fi * 4);
        }
        __syncthreads();

        const int gq = tid >> 6;

        for (int t0 = 0; t0 < n; t0 += GT) {
            const int gv = min(GT, n - t0);
            if (tid < GT) {
                if (tid < gv) {
                    sh.up.gt[tid] = etok[off0 + t0 + tid];
                    sh.up.gw[tid] = ew[off0 + t0 + tid];
                    sh.up.gs[tid] = off0 + t0 + tid;
                } else {
                    sh.up.gt[tid] = etok[off0]; sh.up.gw[tid] = 0.f; sh.up.gs[tid] = nent;
                }
            }
            __syncthreads();

            #pragma unroll
            for (int r = 0; r < 2; ++r) {
                const int idx = tid + r * BLOCK;
                const int g = idx >> 5, pp = idx & 31;
                const size_t row = (size_t)sh.up.gs[g] * PDIM + pp;
                const float s = part[row] + part[PS + row]
                              + part[2 * PS + row] + part[3 * PS + row];
                const float pj = s / (1.f + expf(-s));
                sh.up.projT[pp][g] = pj * sh.up.gw[g];
            }
            __syncthreads();

            float4 o0 = make_float4(0.f, 0.f, 0.f, 0.f);
            float4 o1 = o0, o2 = o0, o3 = o0;
            #pragma unroll
            for (int pp = 0; pp < PDIM; ++pp) {
                const float4 pj4 = *(const float4*)&sh.up.projT[pp][gq * 4];
                const float4 vu4 = *(const float4*)&sh.up.vul[pp * DCH + lane * 4];
                o0.x = fmaf(pj4.x, vu4.x, o0.x); o0.y = fmaf(pj4.x, vu4.y, o0.y);
                o0.z = fmaf(pj4.x, vu4.z, o0.z); o0.w = fmaf(pj4.x, vu4.w, o0.w);
                o1.x = fmaf(pj4.y, vu4.x, o1.x); o1.y = fmaf(pj4.y, vu4.y, o1.y);
                o1.z = fmaf(pj4.y, vu4.z, o1.z); o1.w = fmaf(pj4.y, vu4.w, o1.w);
                o2.x = fmaf(pj4.z, vu4.x, o2.x); o2.y = fmaf(pj4.z, vu4.y, o2.y);
                o2.z = fmaf(pj4.z, vu4.z, o2.z); o2.w = fmaf(pj4.z, vu4.w, o2.w);
                o3.x = fmaf(pj4.w, vu4.x, o3.x); o3.y = fmaf(pj4.w, vu4.y, o3.y);
                o3.z = fmaf(pj4.w, vu4.z, o3.z); o3.w = fmaf(pj4.w, vu4.w, o3.w);
            }

            float4 ov[4] = {o0, o1, o2, o3};
            #pragma unroll
            for (int j = 0; j < 4; ++j)
                *(float4*)(contrib + (size_t)sh.up.gs[gq * 4 + j] * DDIM + c * DCH + lane * 4) = ov[j];
            __syncthreads();
        }
        __syncthreads();
    }

    grid.sync();

    // ------------------------------------------------------------ phase 5: combine
    for (int tb = blockIdx.x * RTPB; tb < ntok; tb += gridDim.x * RTPB) {
        const int tok = tb + wv;
        if (tok < ntok) {
            const int s0 = slotof[tok * TOPK + 0];
            const int s1 = slotof[tok * TOPK + 1];
            const int s2 = slotof[tok * TOPK + 2];
            const int s3 = slotof[tok * TOPK + 3];
            #pragma unroll
            for (int ch = 0; ch < 4; ++ch) {
                const int fi = ch * 64 + lane;       // float4 index in row
                float4 r = ((const float4*)(x + (size_t)tok * DDIM))[fi];
                const float4 c0 = ((const float4*)(contrib + (size_t)s0 * DDIM))[fi];
                const float4 c1 = ((const float4*)(contrib + (size_t)s1 * DDIM))[fi];
                const float4 c2 = ((const float4*)(contrib + (size_t)s2 * DDIM))[fi];
                const float4 c3 = ((const float4*)(contrib + (size_t)s3 * DDIM))[fi];
                r.x += c0.x + c1.x + c2.x + c3.x;
                r.y += c0.y + c1.y + c2.y + c3.y;
                r.z += c0.z + c1.z + c2.z + c3.z;
                r.w += c0.w + c1.w + c2.w + c3.w;
                ((float4*)(out + (size_t)tok * DDIM))[fi] = r;
            }
        }
    }
}

// ===========================================================================
// Fallback path: the verified R8 5-kernel pipeline (verbatim).
// ===========================================================================
__global__ __launch_bounds__(BLOCK) void route_kernel(
    const float* __restrict__ x,
    const float* __restrict__ hasher_w,
    const float* __restrict__ keys,
    int*   __restrict__ tki,
    float* __restrict__ tkw,
    int ntok)
{
    __shared__ float P_s[RTPB][64 * 33];
    __shared__ float h_s[RTPB][32];

    const int tid  = threadIdx.x;
    const int wv   = tid >> 6;
    const int lane = tid & 63;
    const int tok  = min(blockIdx.x * RTPB + wv, ntok - 1);

    const float4* xrow = (const float4*)(x + (size_t)tok * DDIM);
    float4 xr[4];
    #pragma unroll
    for (int i = 0; i < 4; ++i) xr[i] = xrow[i * 64 + lane];

    float part[PDIM];
    #pragma unroll
    for (int pp = 0; pp < PDIM; ++pp) {
        const float4* wrow = (const float4*)(hasher_w + (size_t)pp * DDIM);
        float a = 0.f;
        #pragma unroll
        for (int i = 0; i < 4; ++i) {
            const float4 w4 = wrow[i * 64 + lane];
            a = fmaf(xr[i].x, w4.x, a); a = fmaf(xr[i].y, w4.y, a);
            a = fmaf(xr[i].z, w4.z, a); a = fmaf(xr[i].w, w4.w, a);
        }
        part[pp] = a;
    }

    float* P = P_s[wv];
    #pragma unroll
    for (int pp = 0; pp < PDIM; ++pp) P[lane * 33 + pp] = part[pp];
    __syncthreads();

    {
        const int pp = lane & 31, half = lane >> 5;
        float hsum = 0.f;
        #pragma unroll 8
        for (int i = 0; i < 32; ++i)
            hsum += P[(half * 32 + i) * 33 + pp];
        hsum += __shfl_xor(hsum, 32, 64);
        if (half == 0) h_s[wv][pp] = hsum;
    }
    __syncthreads();

    float4 h4[8];
    #pragma unroll
    for (int i = 0; i < 8; ++i) h4[i] = *(const float4*)&h_s[wv][i * 4];

    float sc0, sc1, sc2, sc3;
    {
        float sv[4];
        #pragma unroll
        for (int c = 0; c < 4; ++c) {
            const float4* kr = (const float4*)(keys + (size_t)(c * 64 + lane) * PDIM);
            float a = 0.f;
            #pragma unroll
            for (int i = 0; i < 8; ++i) {
                const float4 k4 = kr[i];
                a = fmaf(k4.x, h4[i].x, a); a = fmaf(k4.y, h4[i].y, a);
                a = fmaf(k4.z, h4[i].z, a); a = fmaf(k4.w, h4[i].w, a);
            }
            sv[c] = a;
        }
        sc0 = sv[0]; sc1 = sv[1]; sc2 = sv[2]; sc3 = sv[3];
    }

    float wval[TOPK]; int widx[TOPK];
    #pragma unroll
    for (int r = 0; r < TOPK; ++r) {
        float bv = sc0; int bc = 0;
        if (sc1 > bv) { bv = sc1; bc = 1; }
        if (sc2 > bv) { bv = sc2; bc = 2; }
        if (sc3 > bv) { bv = sc3; bc = 3; }
        int bidx = bc * 64 + lane;
        #pragma unroll
        for (int off = 1; off < 64; off <<= 1) {
            const float ov = __shfl_xor(bv, off, 64);
            const int   oi = __shfl_xor(bidx, off, 64);
            if (ov > bv || (ov == bv && oi < bidx)) { bv = ov; bidx = oi; }
        }
        wval[r] = bv; widx[r] = bidx;
        if ((bidx & 63) == lane) {
            const int c = bidx >> 6;
            if (c == 0) sc0 = -FLT_MAX;
            else if (c == 1) sc1 = -FLT_MAX;
            else if (c == 2) sc2 = -FLT_MAX;
            else sc3 = -FLT_MAX;
        }
    }

    if (lane == 0) {
        float m = wval[0];
        #pragma unroll
        for (int k = 1; k < TOPK; ++k) m = fmaxf(m, wval[k]);
        float s = 0.f, e[TOPK];
        #pragma unroll
        for (int k = 0; k < TOPK; ++k) { e[k] = expf(wval[k] - m); s += e[k]; }
        #pragma unroll
        for (int k = 0; k < TOPK; ++k) {
            tki[tok * TOPK + k] = widx[k];
            tkw[tok * TOPK + k] = e[k] / s;
        }
    }
}

__global__ __launch_bounds__(NPAT) void scanfill_kernel(
    const int* __restrict__ tki, const float* __restrict__ tkw,
    const float* __restrict__ scale_p,
    int* __restrict__ offs,
    int* __restrict__ etok, float* __restrict__ ew, int* __restrict__ slotof,
    int nent)
{
    __shared__ int s[NPAT];
    __shared__ int cur[NPAT];
    const int tid = threadIdx.x;

    cur[tid] = 0;
    __syncthreads();
    for (int e = tid; e < nent; e += NPAT) atomicAdd(&cur[tki[e]], 1);
    __syncthreads();

    const int v = cur[tid];
    s[tid] = v;
    __syncthreads();
    for (int off = 1; off < NPAT; off <<= 1) {
        int t = 0;
        if (tid >= off) t = s[tid - off];
        __syncthreads();
        s[tid] += t;
        __syncthreads();
    }
    const int incl = s[tid];
    offs[tid + 1] = incl;
    if (tid == 0) offs[0] = 0;
    cur[tid] = incl - v;
    __syncthreads();

    const float sc = scale_p[0];
    for (int e = tid; e < nent; e += NPAT) {
        const int p = tki[e];
        const int slot = atomicAdd(&cur[p], 1);
        etok[slot] = e >> 2;
        ew[slot]   = tkw[e] * sc;
        slotof[e]  = slot;
    }
}

__global__ __launch_bounds__(BLOCK, 2) void proj_kernel(
    const float* __restrict__ x,
    const float* __restrict__ vd,
    const int* __restrict__ offs,
    const int* __restrict__ etok,
    float* __restrict__ part,
    int nent)
{
    __shared__ float vd_s[DCH * PDIM];
    __shared__ float x_s[GT * DCH];
    __shared__ float red[4][8][68];
    __shared__ int   gt[GT];
    __shared__ int   gs[GT];

    const int p   = blockIdx.x >> 2;
    const int c   = blockIdx.x & 3;
    const int tid = threadIdx.x;
    const int off0 = offs[p];
    const int n    = offs[p + 1] - off0;
    if (n == 0) return;

    const float* vdp = vd + (size_t)p * DDIM * PDIM + (size_t)c * DCH * PDIM;
    #pragma unroll
    for (int k = 0; k < 8; ++k)
        ((float4*)vd_s)[k * 256 + tid] = ((const float4*)vdp)[k * 256 + tid];
    __syncthreads();

    const int pp4 = tid & 7;
    const int seg = tid >> 3;
    float* partc = part + (size_t)c * (size_t)(nent + 1) * PDIM;

    for (int t0 = 0; t0 < n; t0 += GT) {
        const int gv = min(GT, n - t0);
        if (tid < GT) {
            if (tid < gv) { gt[tid] = etok[off0 + t0 + tid]; gs[tid] = off0 + t0 + tid; }
            else          { gt[tid] = etok[off0];            gs[tid] = nent; }
        }
        __syncthreads();

        #pragma unroll
        for (int k = 0; k < 4; ++k) {
            const int q  = k * 256 + tid;
            const int g  = q >> 6, fi = q & 63;
            ((float4*)x_s)[g * 64 + fi] =
                *(const float4*)(x + (size_t)gt[g] * DDIM + c * DCH + fi * 4);
        }
        __syncthreads();

        float4 acc[GT];
        #pragma unroll
        for (int g = 0; g < GT; ++g) acc[g] = make_float4(0.f, 0.f, 0.f, 0.f);

        #pragma unroll
        for (int i4 = 0; i4 < 2; ++i4) {
            const int d0 = seg * 8 + i4 * 4;
            const float4 v0 = *(const float4*)&vd_s[(d0 + 0) * PDIM + pp4 * 4];
            const float4 v1 = *(const float4*)&vd_s[(d0 + 1) * PDIM + pp4 * 4];
            const float4 v2 = *(const float4*)&vd_s[(d0 + 2) * PDIM + pp4 * 4];
            const float4 v3 = *(const float4*)&vd_s[(d0 + 3) * PDIM + pp4 * 4];
            #pragma unroll
            for (int g = 0; g < GT; ++g) {
                const float4 xg = *(const float4*)&x_s[g * DCH + d0];
                acc[g].x = fmaf(xg.x, v0.x, acc[g].x);
                acc[g].y = fmaf(xg.x, v0.y, acc[g].y);
                acc[g].z = fmaf(xg.x, v0.z, acc[g].z);
                acc[g].w = fmaf(xg.x, v0.w, acc[g].w);
                acc[g].x = fmaf(xg.y, v1.x, acc[g].x);
                acc[g].y = fmaf(xg.y, v1.y, acc[g].y);
                acc[g].z = fmaf(xg.y, v1.z, acc[g].z);
                acc[g].w = fmaf(xg.y, v1.w, acc[g].w);
                acc[g].x = fmaf(xg.z, v2.x, acc[g].x);
                acc[g].y = fmaf(xg.z, v2.y, acc[g].y);
                acc[g].z = fmaf(xg.z, v2.z, acc[g].z);
                acc[g].w = fmaf(xg.z, v2.w, acc[g].w);
                acc[g].x = fmaf(xg.w, v3.x, acc[g].x);
                acc[g].y = fmaf(xg.w, v3.y, acc[g].y);
                acc[g].z = fmaf(xg.w, v3.z, acc[g].z);
                acc[g].w = fmaf(xg.w, v3.w, acc[g].w);
            }
        }

        #pragma unroll
        for (int g = 0; g < GT; ++g) {
            #pragma unroll
            for (int off = 8; off <= 32; off <<= 1) {
                acc[g].x += __shfl_xor(acc[g].x, off, 64);
                acc[g].y += __shfl_xor(acc[g].y, off, 64);
                acc[g].z += __shfl_xor(acc[g].z, off, 64);
                acc[g].w += __shfl_xor(acc[g].w, off, 64);
            }
        }
        const int wv = tid >> 6;
        if ((tid & 0x38) == 0) {
            #pragma unroll
            for (int g = 0; g < GT; ++g)
                *(float4*)&red[wv][pp4][g * 4] = acc[g];
        }
        __syncthreads();

        #pragma unroll
        for (int r = 0; r < 2; ++r) {
            const int idx = tid + r * BLOCK;
            const int g = idx >> 5, pp = idx & 31;
            const int q = pp >> 2, cmp = g * 4 + (pp & 3);
            const float s = red[0][q][cmp] + red[1][q][cmp]
                          + red[2][q][cmp] + red[3][q][cmp];
            partc[(size_t)gs[g] * PDIM + pp] = s;
        }
        __syncthreads();
    }
}

template <int MODE>
__global__ __launch_bounds__(BLOCK, 4) void up_kernel(
    const float* __restrict__ vu,
    const int* __restrict__ offs,
    const int* __restrict__ etok,
    const float* __restrict__ ew,
    const float* __restrict__ part,
    float* __restrict__ dst,
    int nent)
{
    __shared__ float vu_s[PDIM * DCH];
    __shared__ float projT[PDIM][20];
    __shared__ int   gt[GT];
    __shared__ float gw[GT];
    __shared__ int   gs[GT];

    const int p   = blockIdx.x >> 2;
    const int c   = blockIdx.x & 3;
    const int tid = threadIdx.x;
    const int off0 = offs[p];
    const int n    = offs[p + 1] - off0;
    if (n == 0) return;

    const size_t PS = (size_t)(nent + 1) * PDIM;

    const float* vup = vu + (size_t)p * PDIM * DDIM + (size_t)c * DCH;
    #pragma unroll
    for (int k = 0; k < 8; ++k) {
        const int q  = k * 256 + tid;
        const int pp = q >> 6, fi = q & 63;
        *(float4*)&vu_s[pp * DCH + fi * 4] =
            *(const float4*)(vup + (size_t)pp * DDIM + fi * 4);
    }
    __syncthreads();

    const int gq   = tid >> 6;
    const int lane = tid & 63;

    for (int t0 = 0; t0 < n; t0 += GT) {
        const int gv = min(GT, n - t0);
        if (tid < GT) {
            if (tid < gv) {
                gt[tid] = etok[off0 + t0 + tid];
                gw[tid] = ew[off0 + t0 + tid];
                gs[tid] = off0 + t0 + tid;
            } else {
                gt[tid] = etok[off0]; gw[tid] = 0.f; gs[tid] = nent;
            }
        }
        __syncthreads();

        #pragma unroll
        for (int r = 0; r < 2; ++r) {
            const int idx = tid + r * BLOCK;
            const int g = idx >> 5, pp = idx & 31;
            const size_t row = (size_t)gs[g] * PDIM + pp;
            const float s = part[row] + part[PS + row]
                          + part[2 * PS + row] + part[3 * PS + row];
            const float pj = s / (1.f + expf(-s));
            projT[pp][g] = pj * gw[g];
        }
        __syncthreads();

        float4 o0 = make_float4(0.f, 0.f, 0.f, 0.f);
        float4 o1 = o0, o2 = o0, o3 = o0;
        #pragma unroll
        for (int pp = 0; pp < PDIM; ++pp) {
            const float4 pj4 = *(const float4*)&projT[pp][gq * 4];
            const float4 vu4 = *(const float4*)&vu_s[pp * DCH + lane * 4];
            o0.x = fmaf(pj4.x, vu4.x, o0.x); o0.y = fmaf(pj4.x, vu4.y, o0.y);
            o0.z = fmaf(pj4.x, vu4.z, o0.z); o0.w = fmaf(pj4.x, vu4.w, o0.w);
            o1.x = fmaf(pj4.y, vu4.x, o1.x); o1.y = fmaf(pj4.y, vu4.y, o1.y);
            o1.z = fmaf(pj4.y, vu4.z, o1.z); o1.w = fmaf(pj4.y, vu4.w, o1.w);
            o2.x = fmaf(pj4.z, vu4.x, o2.x); o2.y = fmaf(pj4.z, vu4.y, o2.y);
            o2.z = fmaf(pj4.z, vu4.z, o2.z); o2.w = fmaf(pj4.z, vu4.w, o2.w);
            o3.x = fmaf(pj4.w, vu4.x, o3.x); o3.y = fmaf(pj4.w, vu4.y, o3.y);
            o3.z = fmaf(pj4.w, vu4.z, o3.z); o3.w = fmaf(pj4.w, vu4.w, o3.w);
        }

        float4 ov[4] = {o0, o1, o2, o3};
        if (MODE == 0) {
            #pragma unroll
            for (int j = 0; j < 4; ++j)
                *(float4*)(dst + (size_t)gs[gq * 4 + j] * DDIM + c * DCH + lane * 4) = ov[j];
        } else {
            #pragma unroll
            for (int j = 0; j < 4; ++j) {
                const int g = gq * 4 + j;
                if (g < gv) {
                    float* op = dst + (size_t)gt[g] * DDIM + c * DCH + lane * 4;
                    atomicAdd(op + 0, ov[j].x);
                    atomicAdd(op + 1, ov[j].y);
                    atomicAdd(op + 2, ov[j].z);
                    atomicAdd(op + 3, ov[j].w);
                }
            }
        }
        __syncthreads();
    }
}

__global__ __launch_bounds__(BLOCK) void combine_kernel(
    const float* __restrict__ x, const float* __restrict__ contrib,
    const int* __restrict__ slotof, float* __restrict__ out)
{
    __shared__ int sl[TOPK];
    const int t = blockIdx.x, tid = threadIdx.x;
    if (tid < TOPK) sl[tid] = slotof[t * TOPK + tid];
    __syncthreads();
    float4 r = ((const float4*)(x + (size_t)t * DDIM))[tid];
    #pragma unroll
    for (int k = 0; k < TOPK; ++k) {
        const float4 cv = ((const float4*)(contrib + (size_t)sl[k] * DDIM))[tid];
        r.x += cv.x; r.y += cv.y; r.z += cv.z; r.w += cv.w;
    }
    ((float4*)(out + (size_t)t * DDIM))[tid] = r;
}

// ---------------------------------------------------------------------------
extern "C" void kernel_launch(void* const* d_in, const int* in_sizes, int n_in,
                              void* d_out, int out_size, void* d_ws, size_t ws_size,
                              hipStream_t stream) {
    const float* x        = (const float*)d_in[0];
    const float* hasher_w = (const float*)d_in[1];
    const float* keys     = (const float*)d_in[2];
    const float* vd       = (const float*)d_in[3];
    const float* vu       = (const float*)d_in[4];
    const float* scale    = (const float*)d_in[5];
    float* out = (float*)d_out;

    int ntok = in_sizes[0] / DDIM;        // B*T
    int nent = ntok * TOPK;

    // workspace layout
    char* w = (char*)d_ws;
    const size_t o_offs = 1024;                                   // 257 int
    const size_t o_tki  = 2560;                                   // nent int
    const size_t o_tkw  = o_tki  + (size_t)nent * 4;
    const size_t o_etok = o_tkw  + (size_t)nent * 4;
    const size_t o_ew   = o_etok + (size_t)nent * 4;
    const size_t o_slot = o_ew   + (size_t)nent * 4;
    const size_t o_part = (o_slot + (size_t)nent * 4 + 255) & ~(size_t)255;
    const size_t partsz = (size_t)NCH * (size_t)(nent + 1) * PDIM * 4;
    const size_t o_ctb  = (o_part + partsz + 255) & ~(size_t)255;
    const size_t needPart    = o_ctb;
    const size_t needContrib = o_ctb + (size_t)(nent + 1) * DDIM * 4;

    int*   offs   = (int*)(w + o_offs);
    int*   tki    = (int*)(w + o_tki);
    float* tkw    = (float*)(w + o_tkw);
    int*   etok   = (int*)(w + o_etok);
    float* ew     = (float*)(w + o_ew);
    int*   slotof = (int*)(w + o_slot);
    float* part   = (float*)(w + o_part);
    float* contrib= (float*)(w + o_ctb);

    bool launched = false;
    if (ws_size >= needContrib) {
        void* cargs[] = {
            (void*)&x, (void*)&hasher_w, (void*)&keys, (void*)&vd, (void*)&vu,
            (void*)&scale, (void*)&out, (void*)&tki, (void*)&tkw, (void*)&offs,
            (void*)&etok, (void*)&ew, (void*)&slotof, (void*)&part,
            (void*)&contrib, (void*)&ntok, (void*)&nent
        };
        hipError_t cerr = hipLaunchCooperativeKernel(
            (const void*)fused_kernel, dim3(GRID), dim3(BLOCK), cargs, 0, stream);
        if (cerr == hipSuccess) launched = true;
        else (void)hipGetLastError();   // clear and fall back
    }

    if (!launched) {
        const int rblocks = (ntok + RTPB - 1) / RTPB;
        hipLaunchKernelGGL(route_kernel, dim3(rblocks), dim3(BLOCK), 0, stream,
                           x, hasher_w, keys, tki, tkw, ntok);
        hipLaunchKernelGGL(scanfill_kernel, dim3(1), dim3(NPAT), 0, stream,
                           tki, tkw, scale, offs, etok, ew, slotof, nent);
        hipLaunchKernelGGL(proj_kernel, dim3(NPAT * NCH), dim3(BLOCK), 0, stream,
                           x, vd, offs, etok, part, nent);
        if (ws_size >= needContrib) {
            hipLaunchKernelGGL((up_kernel<0>), dim3(NPAT * NCH), dim3(BLOCK), 0, stream,
                               vu, offs, etok, ew, part, contrib, nent);
            hipLaunchKernelGGL(combine_kernel, dim3(ntok), dim3(BLOCK), 0, stream,
                               x, contrib, slotof, out);
        } else if (ws_size >= needPart) {
            hipMemcpyAsync(out, x, (size_t)ntok * DDIM * 4, hipMemcpyDeviceToDevice,
                           stream);
            hipLaunchKernelGGL((up_kernel<1>), dim3(NPAT * NCH), dim3(BLOCK), 0, stream,
                               vu, offs, etok, ew, part, out, nent);
        }
    }
}